// Round 11
// baseline (106.357 us; speedup 1.0000x reference)
//
#include <hip/hip_runtime.h>

// ---------------------------------------------------------------------------
// LModel15: edge sampling + bilinear similarity loss (MI355X / gfx950)
// Outputs: [similarity_loss, normal_loss, normalization_loss] (3x fp32)
// R11: dual-pixel RGB565 texture. dual[y][x] = (pix[x], pix[x+1 clamped]) as
//      2x16bit in one 4B word -> one load covers both bilinear columns of a
//      row: 4 gathers/sample instead of 8 (R9/R10 were TA-lookup-bound:
//      VALUBusy 28%, HBM 5%, barrier-insensitive). Sample structure = R9
//      (measured faster than R10). Scan+transform merged in prep_kernel.
// ---------------------------------------------------------------------------

constexpr int NVS   = 10;
constexpr int IMG_H = 2000;
constexpr int IMG_W = 3000;
constexpr int NPIX  = IMG_H * IMG_W;
constexpr int QROW  = IMG_W / 4;          // 750 quads per row (exact)
constexpr int SAMPLE_BLOCKS = 2048;
constexpr unsigned CHUNK = 512;           // samples per chunk (2 per thread)

typedef float    fx4 __attribute__((ext_vector_type(4)));
typedef unsigned ux4 __attribute__((ext_vector_type(4)));

struct Geom {
    float p0x, p0y, p0z;
    float p1x, p1y, p1z;
    float p2x, p2y, p2z;
    float p3x, p3y, p3z;
    float cdx, cdy, cdz;
    float cnx, cny, cnz;
    float cux, cuy, cuz;
    float len;
    int   nh;
};

__device__ __forceinline__ Geom compute_geom(const float* __restrict__ ep, int e) {
    Geom g;
    const float* p = ep + (size_t)e * 12;
    g.p0x = p[0];  g.p0y = p[1];  g.p0z = p[2];
    g.p1x = p[3];  g.p1y = p[4];  g.p1z = p[5];
    g.p2x = p[6];  g.p2y = p[7];  g.p2z = p[8];
    g.p3x = p[9];  g.p3y = p[10]; g.p3z = p[11];

    float dx = g.p1x - g.p0x, dy = g.p1y - g.p0y, dz = g.p1z - g.p0z;
    float ax = dx + 1e-6f, ay = dy + 1e-6f, az = dz + 1e-6f;
    g.len = sqrtf(ax * ax + ay * ay + az * az);
    g.cdx = dx / g.len; g.cdy = dy / g.len; g.cdz = dz / g.len;

    float ndx = g.p3x - g.p1x, ndy = g.p3y - g.p1y, ndz = g.p3z - g.p1z;
    float cnx = g.cdy * ndz - g.cdz * ndy;
    float cny = g.cdz * ndx - g.cdx * ndz;
    float cnz = g.cdx * ndy - g.cdy * ndx;
    float n1 = sqrtf(cnx * cnx + cny * cny + cnz * cnz) + 1e-8f;
    cnx /= n1; cny /= n1; cnz /= n1;
    if (cnz > 0.f) { cnx = -cnx; cny = -cny; cnz = -cnz; }
    g.cnx = cnx; g.cny = cny; g.cnz = cnz;

    float cux = cny * g.cdz - cnz * g.cdy;
    float cuy = cnz * g.cdx - cnx * g.cdz;
    float cuz = cnx * g.cdy - cny * g.cdx;
    float n2 = sqrtf(cux * cux + cuy * cuy + cuz * cuz) + 1e-8f;
    g.cux = cux / n2; g.cuy = cuy / n2; g.cuz = cuz / n2;

    int nh = (int)floorf(g.len / 0.05f);
    g.nh = nh < 2 ? 2 : (nh > 1000 ? 1000 : nh);
    return g;
}

__device__ __forceinline__ double block_reduce_d(double v) {
    __shared__ double sh[256];
    int tid = threadIdx.x;
    sh[tid] = v;
    __syncthreads();
    for (int s = 128; s > 0; s >>= 1) {
        if (tid < s) sh[tid] += sh[tid + s];
        __syncthreads();
    }
    double r = sh[0];
    __syncthreads();
    return r;
}

// ---------------------------------------------------------------------------
// per-edge losses + per-edge geometry store
// ---------------------------------------------------------------------------
__global__ __launch_bounds__(256) void edge_kernel(
        const float* __restrict__ ep, int E,
        double* __restrict__ normal_part,
        double* __restrict__ norz_part,
        fx4* __restrict__ geom_out,
        int* __restrict__ nh_out) {
    int e = blockIdx.x * blockDim.x + threadIdx.x;
    double t1 = 0.0, t2 = 0.0;
    if (e < E) {
        Geom g = compute_geom(ep, e);
        float pdx = g.p0x - g.p2x, pdy = g.p0y - g.p2y, pdz = g.p0z - g.p2z;
        float pnx = pdy * g.cdz - pdz * g.cdy;
        float pny = pdz * g.cdx - pdx * g.cdz;
        float pnz = pdx * g.cdy - pdy * g.cdx;
        float n = sqrtf(pnx * pnx + pny * pny + pnz * pnz) + 1e-8f;
        pnx /= n; pny /= n; pnz /= n;
        float dotn = g.cnx * pnx + g.cny * pny + g.cnz * pnz;
        t1 = (double)(1.0f - dotn);

        float ox = g.p0y * g.p1z - g.p0z * g.p1y;
        float oy = g.p0z * g.p1x - g.p0x * g.p1z;
        float oz = g.p0x * g.p1y - g.p0y * g.p1x;
        float no = sqrtf(ox * ox + oy * oy + oz * oz) + 1e-8f;
        ox /= no; oy /= no; oz /= no;
        float snp = fminf(fabsf(g.cux * ox + g.cuy * oy + g.cuz * oz), 0.5f);
        t2 = (double)(1.0f - snp / 0.5f);

        fx4 f0 = {g.cdx, g.cdy, g.cdz, g.len};
        fx4 f1 = {g.cux, g.cuy, g.cuz, 1.0f / (float)(g.nh - 1)};
        fx4 f2 = {g.p0x, g.p0y, g.p0z, 0.f};
        geom_out[e * 3 + 0] = f0;
        geom_out[e * 3 + 1] = f1;
        geom_out[e * 3 + 2] = f2;
        nh_out[e] = g.nh;
    }
    double s1 = block_reduce_d(t1);
    double s2 = block_reduce_d(t2);
    if (threadIdx.x == 0) {
        normal_part[blockIdx.x] = s1;
        norz_part[blockIdx.x]   = s2;
    }
}

// ---------------------------------------------------------------------------
// prep: thread-coarsened prefix scan of nh*10 -> cum, plus (thread 0)
// transform = K2h @ E2 @ inv(E1). One launch.
// ---------------------------------------------------------------------------
__global__ __launch_bounds__(256) void prep_kernel(
        const int* __restrict__ nh, int E, unsigned* __restrict__ cum,
        const float* __restrict__ K2, const float* __restrict__ E1,
        const float* __restrict__ E2, float* __restrict__ tf) {
    __shared__ unsigned ssum[256];
    int tid = threadIdx.x;
    int K = (E + 255) / 256;
    int base = tid * K;

    unsigned s = 0;
    for (int k = 0; k < K; ++k) {
        int idx = base + k;
        if (idx < E) s += (unsigned)(nh[idx] * NVS);
    }
    ssum[tid] = s;
    __syncthreads();
    for (int off = 1; off < 256; off <<= 1) {
        unsigned add = (tid >= off) ? ssum[tid - off] : 0u;
        __syncthreads();
        ssum[tid] += add;
        __syncthreads();
    }
    unsigned run = ssum[tid] - s;
    for (int k = 0; k < K; ++k) {
        int idx = base + k;
        if (idx < E) {
            run += (unsigned)(nh[idx] * NVS);
            cum[idx + 1] = run;
        }
    }
    if (tid == 0) {
        cum[0] = 0;

        double a[4][8];
        for (int r = 0; r < 4; ++r)
            for (int c = 0; c < 4; ++c) {
                a[r][c] = (double)E1[r * 4 + c];
                a[r][4 + c] = (r == c) ? 1.0 : 0.0;
            }
        for (int col = 0; col < 4; ++col) {
            int piv = col; double best = fabs(a[col][col]);
            for (int r = col + 1; r < 4; ++r) {
                double t = fabs(a[r][col]);
                if (t > best) { best = t; piv = r; }
            }
            if (piv != col)
                for (int c = 0; c < 8; ++c) { double t = a[col][c]; a[col][c] = a[piv][c]; a[piv][c] = t; }
            double d = a[col][col];
            for (int c = 0; c < 8; ++c) a[col][c] /= d;
            for (int r = 0; r < 4; ++r) {
                if (r == col) continue;
                double f = a[r][col];
                for (int c = 0; c < 8; ++c) a[r][c] -= f * a[col][c];
            }
        }
        double inv1[4][4];
        for (int r = 0; r < 4; ++r)
            for (int c = 0; c < 4; ++c) inv1[r][c] = a[r][4 + c];

        double k2h[4][4];
        for (int r = 0; r < 4; ++r)
            for (int c = 0; c < 4; ++c) k2h[r][c] = (r == c) ? 1.0 : 0.0;
        for (int r = 0; r < 3; ++r)
            for (int c = 0; c < 3; ++c) k2h[r][c] = (double)K2[r * 3 + c];

        double m1[4][4];
        for (int r = 0; r < 4; ++r)
            for (int c = 0; c < 4; ++c) {
                double sm = 0.0;
                for (int k = 0; k < 4; ++k) sm += (double)E2[r * 4 + k] * inv1[k][c];
                m1[r][c] = sm;
            }
        for (int r = 0; r < 4; ++r)
            for (int c = 0; c < 4; ++c) {
                double sm = 0.0;
                for (int k = 0; k < 4; ++k) sm += k2h[r][k] * m1[k][c];
                tf[r * 4 + c] = (float)sm;
            }
    }
}

// ---------------------------------------------------------------------------
// pack helpers: RGB565 dual-pixel. word = p565(x) | p565(x+1)<<16
// ---------------------------------------------------------------------------
__device__ __forceinline__ unsigned p565(float r, float g, float b) {
    unsigned ri = (unsigned)__float2int_rn(r * 31.0f) & 31u;
    unsigned gi = (unsigned)__float2int_rn(g * 63.0f) & 63u;
    unsigned bi = (unsigned)__float2int_rn(b * 31.0f) & 31u;
    return ri | (gi << 5) | (bi << 11);
}

__global__ __launch_bounds__(256) void repack_kernel(
        const float* __restrict__ img1, const float* __restrict__ img2,
        unsigned* __restrict__ o1, unsigned* __restrict__ o2) {
    const int nq = NPIX / 4;
    int idx = blockIdx.x * blockDim.x + threadIdx.x;
    if (idx >= 2 * nq) return;
    const float* img;
    unsigned* out;
    int q;
    if (idx < nq) { img = img1; out = o1; q = idx; }
    else          { img = img2; out = o2; q = idx - nq; }

    fx4 r = __builtin_nontemporal_load(reinterpret_cast<const fx4*>(img) + q);
    fx4 g = __builtin_nontemporal_load(reinterpret_cast<const fx4*>(img + NPIX) + q);
    fx4 b = __builtin_nontemporal_load(reinterpret_cast<const fx4*>(img + 2 * (size_t)NPIX) + q);

    // next pixel (first pixel of next quad in same row), or dup of last col
    float rn, gn, bn;
    int qrow = q % QROW;
    if (qrow == QROW - 1) { rn = r.w; gn = g.w; bn = b.w; }
    else {
        int nx = q * 4 + 4;
        rn = img[nx];
        gn = img[NPIX + nx];
        bn = img[2 * (size_t)NPIX + nx];
    }

    unsigned h0 = p565(r.x, g.x, b.x);
    unsigned h1 = p565(r.y, g.y, b.y);
    unsigned h2 = p565(r.z, g.z, b.z);
    unsigned h3 = p565(r.w, g.w, b.w);
    unsigned h4 = p565(rn, gn, bn);
    ux4 o;
    o.x = h0 | (h1 << 16);
    o.y = h1 | (h2 << 16);
    o.z = h2 | (h3 << 16);
    o.w = h3 | (h4 << 16);
    reinterpret_cast<ux4*>(out)[q] = o;
}

// ---------------------------------------------------------------------------
// bilinear sample of dual-565 texture: 2x 4B gathers (rows y0, y1).
// Returns channels in [0,31]/[0,63]/[0,31] scale.
// ---------------------------------------------------------------------------
__device__ __forceinline__ void sample565(const unsigned* __restrict__ img,
                                          float u, float v,
                                          float& r, float& g, float& b) {
    float x = u * (float)IMG_W - 0.5f;
    float y = v * (float)IMG_H - 0.5f;
    float x0 = floorf(x), y0 = floorf(y);
    float wx = x - x0, wy = y - y0;
    int x0i = (int)x0; x0i = x0i < 0 ? 0 : (x0i > IMG_W - 1 ? IMG_W - 1 : x0i);
    int y0i = (int)y0; y0i = y0i < 0 ? 0 : (y0i > IMG_H - 1 ? IMG_H - 1 : y0i);
    int y1i = y0i + 1; y1i = y1i > IMG_H - 1 ? IMG_H - 1 : y1i;

    unsigned t0 = img[(size_t)y0i * IMG_W + x0i];   // (x0, x1) row y0
    unsigned t1 = img[(size_t)y1i * IMG_W + x0i];   // (x0, x1) row y1

    float w00 = (1.f - wx) * (1.f - wy);
    float w10 = wx * (1.f - wy);
    float w01 = (1.f - wx) * wy;
    float w11 = wx * wy;

    r = w00 * (float)(t0 & 31u)         + w10 * (float)((t0 >> 16) & 31u)
      + w01 * (float)(t1 & 31u)         + w11 * (float)((t1 >> 16) & 31u);
    g = w00 * (float)((t0 >> 5) & 63u)  + w10 * (float)((t0 >> 21) & 63u)
      + w01 * (float)((t1 >> 5) & 63u)  + w11 * (float)((t1 >> 21) & 63u);
    b = w00 * (float)((t0 >> 11) & 31u) + w10 * (float)(t0 >> 27)
      + w01 * (float)((t1 >> 11) & 31u) + w11 * (float)(t1 >> 27);
}

// fp32 CHW fallback
__device__ __forceinline__ void bilinear3(const float* __restrict__ img,
                                          float u, float v,
                                          float& r, float& g, float& b) {
    float x = u * (float)IMG_W - 0.5f;
    float y = v * (float)IMG_H - 0.5f;
    float x0 = floorf(x), y0 = floorf(y);
    float wx = x - x0, wy = y - y0;
    int x0i = (int)x0; x0i = x0i < 0 ? 0 : (x0i > IMG_W - 1 ? IMG_W - 1 : x0i);
    int x1i = x0i + 1; x1i = x1i > IMG_W - 1 ? IMG_W - 1 : x1i;
    int y0i = (int)y0; y0i = y0i < 0 ? 0 : (y0i > IMG_H - 1 ? IMG_H - 1 : y0i);
    int y1i = y0i + 1; y1i = y1i > IMG_H - 1 ? IMG_H - 1 : y1i;
    float w00 = (1.f - wx) * (1.f - wy);
    float w10 = wx * (1.f - wy);
    float w01 = (1.f - wx) * wy;
    float w11 = wx * wy;
    float out[3];
#pragma unroll
    for (int c = 0; c < 3; ++c) {
        const float* p = img + (size_t)c * NPIX;
        float v00 = p[(size_t)y0i * IMG_W + x0i];
        float v10 = p[(size_t)y0i * IMG_W + x1i];
        float v01 = p[(size_t)y1i * IMG_W + x0i];
        float v11 = p[(size_t)y1i * IMG_W + x1i];
        out[c] = v00 * w00 + v10 * w10 + v01 * w01 + v11 * w11;
    }
    r = out[0]; g = out[1]; b = out[2];
}

__device__ __forceinline__ int find_edge(const unsigned* __restrict__ cum,
                                         int E, unsigned s) {
    int lo = 0, hi = E - 1;
    while (lo < hi) {
        int mid = (lo + hi + 1) >> 1;
        if (cum[mid] <= s) lo = mid; else hi = mid - 1;
    }
    return lo;
}

// ---------------------------------------------------------------------------
// flattened sampling (R9 structure): grid-stride over 512-sample chunks,
// 2 samples/thread, register accumulation, ONE block reduce at the end.
// ---------------------------------------------------------------------------
template <bool PACKED>
__global__ __launch_bounds__(256) void sample_kernel_t(
        const fx4* __restrict__ geom,
        const unsigned* __restrict__ cum, int E,
        const void* __restrict__ vimg1,
        const void* __restrict__ vimg2,
        const float* __restrict__ K1,
        const float* __restrict__ tf,
        double* __restrict__ sim_part) {
    __shared__ int sh_ea[2], sh_eb[2];
    int tid = threadIdx.x;

    unsigned NS = cum[E];
    unsigned nch = (NS + CHUNK - 1u) / CHUNK;

    float k00 = K1[0], k01 = K1[1], k02 = K1[2];
    float k10 = K1[3], k11 = K1[4], k12 = K1[5];
    float k20 = K1[6], k21 = K1[7], k22 = K1[8];
    float t00 = tf[0],  t01 = tf[1],  t02 = tf[2],  t03 = tf[3];
    float t10 = tf[4],  t11 = tf[5],  t12 = tf[6],  t13 = tf[7];
    float t20 = tf[8],  t21 = tf[9],  t22 = tf[10], t23 = tf[11];

    const unsigned* img1 = (const unsigned*)vimg1;
    const unsigned* img2 = (const unsigned*)vimg2;
    const float* fimg1 = (const float*)vimg1;
    const float* fimg2 = (const float*)vimg2;

    const float INV31 = 1.0f / 31.0f;
    const float INV63 = 1.0f / 63.0f;

    double lsum = 0.0;
    int it = 0;

    auto sample_one = [&](unsigned s, int e) {
        while (e + 1 < E && cum[e + 1] <= s) ++e;
        unsigned q = s - cum[e];
        int i = (int)(q / (unsigned)NVS);
        int j = (int)(q - (unsigned)(i * NVS));

        fx4 f0 = geom[e * 3 + 0];
        fx4 f1 = geom[e * 3 + 1];
        fx4 f2 = geom[e * 3 + 2];

        float dxv = ((float)i * f1.w) * f0.w;
        float dyv = ((float)j / 9.0f) * 0.5f;

        float px = f0.x * dxv + f1.x * dyv + f2.x;
        float py = f0.y * dxv + f1.y * dyv + f2.y;
        float pz = f0.z * dxv + f1.z * dyv + f2.z;

        float w1 = k20 * px + k21 * py + k22 * pz;
        float u1 = (k00 * px + k01 * py + k02 * pz) / w1;
        float v1 = (k10 * px + k11 * py + k12 * pz) / w1;
        u1 = fminf(fmaxf(u1, 0.f), 0.999999f);
        v1 = fminf(fmaxf(v1, 0.f), 0.999999f);

        float w2 = t20 * px + t21 * py + t22 * pz + t23;
        float u2 = (t00 * px + t01 * py + t02 * pz + t03) / w2;
        float v2 = (t10 * px + t11 * py + t12 * pz + t13) / w2;
        u2 = fminf(fmaxf(u2, 0.f), 0.999999f);
        v2 = fminf(fmaxf(v2, 0.f), 0.999999f);

        if constexpr (PACKED) {
            float ar, ag, ab, br, bg, bb;
            sample565(img1, u1, v1, ar, ag, ab);
            sample565(img2, u2, v2, br, bg, bb);
            float dr = (ar - br) * INV31;
            float dg = (ag - bg) * INV63;
            float db = (ab - bb) * INV31;
            lsum += (double)(dr * dr) + (double)(dg * dg) + (double)(db * db);
        } else {
            float ar, ag, ab, br, bg, bb;
            bilinear3(fimg1, u1, v1, ar, ag, ab);
            bilinear3(fimg2, u2, v2, br, bg, bb);
            float dr = ar - br, dg = ag - bg, db = ab - bb;
            lsum += (double)(dr * dr) + (double)(dg * dg) + (double)(db * db);
        }
    };

    for (unsigned chunk = blockIdx.x; chunk < nch; chunk += gridDim.x, ++it) {
        unsigned sbase = chunk * CHUNK;
        int par = it & 1;
        if (tid == 0) {
            sh_ea[par] = find_edge(cum, E, sbase);
            unsigned smid = sbase + 256u;
            sh_eb[par] = find_edge(cum, E, smid < NS ? smid : NS - 1u);
        }
        __syncthreads();
        int ea = sh_ea[par];
        int eb = sh_eb[par];

        unsigned sA = sbase + (unsigned)tid;
        unsigned sB = sA + 256u;
        if (sA < NS) sample_one(sA, ea);
        if (sB < NS) sample_one(sB, eb);
    }

    double tot = block_reduce_d(lsum);
    if (tid == 0) sim_part[blockIdx.x] = tot;
}

// ---------------------------------------------------------------------------
// finalize
// ---------------------------------------------------------------------------
__global__ __launch_bounds__(256) void finalize_kernel(
        const double* __restrict__ sim_part, int n_sim,
        const unsigned* __restrict__ cum, int E,
        const double* __restrict__ normal_part,
        const double* __restrict__ norz_part, int n_a,
        float* __restrict__ out) {
    int tid = threadIdx.x;
    unsigned NS = cum[E];

    double s = 0.0;
    for (int i = tid; i < n_sim; i += 256) s += sim_part[i];
    double sim = block_reduce_d(s);

    s = 0.0;
    for (int i = tid; i < n_a; i += 256) s += normal_part[i];
    double nrm = block_reduce_d(s);

    s = 0.0;
    for (int i = tid; i < n_a; i += 256) s += norz_part[i];
    double nz = block_reduce_d(s);

    if (tid == 0) {
        double total = (double)NS * 3.0;
        out[0] = (float)(sim / total);
        out[1] = (float)((nrm / (double)E) * 0.5);
        out[2] = (float)(nz / (double)E);
    }
}

// ---------------------------------------------------------------------------
extern "C" void kernel_launch(void* const* d_in, const int* in_sizes, int n_in,
                              void* d_out, int out_size, void* d_ws, size_t ws_size,
                              hipStream_t stream) {
    const float* ep  = (const float*)d_in[0];
    const float* im1 = (const float*)d_in[1];
    const float* im2 = (const float*)d_in[2];
    const float* K1  = (const float*)d_in[3];
    const float* K2  = (const float*)d_in[4];
    const float* E1  = (const float*)d_in[5];
    const float* E2  = (const float*)d_in[6];
    float* out = (float*)d_out;

    int E  = in_sizes[0] / 12;
    int nA = (E + 255) / 256;

    size_t img_bytes = (size_t)NPIX * 4;   // dual-565, 4B/pixel

    char* ws = (char*)d_ws;
    size_t off = 0;
    auto alloc = [&](size_t bytes) {
        size_t o = off;
        off = (off + bytes + 255) & ~(size_t)255;
        return (void*)(ws + o);
    };

    fx4*      geom        = (fx4*)alloc((size_t)E * 48);
    int*      nh_arr      = (int*)alloc((size_t)E * 4);
    unsigned* cum         = (unsigned*)alloc((size_t)(E + 1) * 4);
    float*    tf          = (float*)alloc(64);
    double*   sim_part    = (double*)alloc((size_t)SAMPLE_BLOCKS * 8);
    double*   normal_part = (double*)alloc((size_t)nA * 8);
    double*   norz_part   = (double*)alloc((size_t)nA * 8);
    size_t tail_bytes = off;

    bool packed = ws_size >= tail_bytes + 2 * img_bytes + 512;
    unsigned* p1 = nullptr;
    unsigned* p2 = nullptr;
    if (packed) {
        p1 = (unsigned*)alloc(img_bytes);
        p2 = (unsigned*)alloc(img_bytes);
    }

    edge_kernel<<<nA, 256, 0, stream>>>(ep, E, normal_part, norz_part, geom, nh_arr);
    prep_kernel<<<1, 256, 0, stream>>>(nh_arr, E, cum, K2, E1, E2, tf);
    if (packed) {
        const int nq2 = 2 * (NPIX / 4);
        repack_kernel<<<(nq2 + 255) / 256, 256, 0, stream>>>(im1, im2, p1, p2);
        sample_kernel_t<true><<<SAMPLE_BLOCKS, 256, 0, stream>>>(
            geom, cum, E, (const void*)p1, (const void*)p2, K1, tf, sim_part);
    } else {
        sample_kernel_t<false><<<SAMPLE_BLOCKS, 256, 0, stream>>>(
            geom, cum, E, (const void*)im1, (const void*)im2, K1, tf, sim_part);
    }
    finalize_kernel<<<1, 256, 0, stream>>>(sim_part, SAMPLE_BLOCKS, cum, E,
                                           normal_part, norz_part, nA, out);
}

// Round 12
// 92.908 us; speedup vs baseline: 1.1448x; 1.1448x over previous
//
#include <hip/hip_runtime.h>

// ---------------------------------------------------------------------------
// LModel15: edge sampling + bilinear similarity loss (MI355X / gfx950)
// Outputs: [similarity_loss, normal_loss, normalization_loss] (3x fp32)
// R12: R11 (dual-pixel RGB565 texture, 4 gathers/sample) with repack fixed:
//      neighbor pixel obtained via __shfl_down within the wave instead of
//      3 scalar global re-reads (which defeated the nontemporal stream and
//      cost 2x repack time in R11: 74us, FETCH 129MB, 2.4TB/s).
// ---------------------------------------------------------------------------

constexpr int NVS   = 10;
constexpr int IMG_H = 2000;
constexpr int IMG_W = 3000;
constexpr int NPIX  = IMG_H * IMG_W;
constexpr int QROW  = IMG_W / 4;          // 750 quads per row (exact)
constexpr int SAMPLE_BLOCKS = 2048;
constexpr unsigned CHUNK = 512;           // samples per chunk (2 per thread)

typedef float    fx4 __attribute__((ext_vector_type(4)));
typedef unsigned ux4 __attribute__((ext_vector_type(4)));

struct Geom {
    float p0x, p0y, p0z;
    float p1x, p1y, p1z;
    float p2x, p2y, p2z;
    float p3x, p3y, p3z;
    float cdx, cdy, cdz;
    float cnx, cny, cnz;
    float cux, cuy, cuz;
    float len;
    int   nh;
};

__device__ __forceinline__ Geom compute_geom(const float* __restrict__ ep, int e) {
    Geom g;
    const float* p = ep + (size_t)e * 12;
    g.p0x = p[0];  g.p0y = p[1];  g.p0z = p[2];
    g.p1x = p[3];  g.p1y = p[4];  g.p1z = p[5];
    g.p2x = p[6];  g.p2y = p[7];  g.p2z = p[8];
    g.p3x = p[9];  g.p3y = p[10]; g.p3z = p[11];

    float dx = g.p1x - g.p0x, dy = g.p1y - g.p0y, dz = g.p1z - g.p0z;
    float ax = dx + 1e-6f, ay = dy + 1e-6f, az = dz + 1e-6f;
    g.len = sqrtf(ax * ax + ay * ay + az * az);
    g.cdx = dx / g.len; g.cdy = dy / g.len; g.cdz = dz / g.len;

    float ndx = g.p3x - g.p1x, ndy = g.p3y - g.p1y, ndz = g.p3z - g.p1z;
    float cnx = g.cdy * ndz - g.cdz * ndy;
    float cny = g.cdz * ndx - g.cdx * ndz;
    float cnz = g.cdx * ndy - g.cdy * ndx;
    float n1 = sqrtf(cnx * cnx + cny * cny + cnz * cnz) + 1e-8f;
    cnx /= n1; cny /= n1; cnz /= n1;
    if (cnz > 0.f) { cnx = -cnx; cny = -cny; cnz = -cnz; }
    g.cnx = cnx; g.cny = cny; g.cnz = cnz;

    float cux = cny * g.cdz - cnz * g.cdy;
    float cuy = cnz * g.cdx - cnx * g.cdz;
    float cuz = cnx * g.cdy - cny * g.cdx;
    float n2 = sqrtf(cux * cux + cuy * cuy + cuz * cuz) + 1e-8f;
    g.cux = cux / n2; g.cuy = cuy / n2; g.cuz = cuz / n2;

    int nh = (int)floorf(g.len / 0.05f);
    g.nh = nh < 2 ? 2 : (nh > 1000 ? 1000 : nh);
    return g;
}

__device__ __forceinline__ double block_reduce_d(double v) {
    __shared__ double sh[256];
    int tid = threadIdx.x;
    sh[tid] = v;
    __syncthreads();
    for (int s = 128; s > 0; s >>= 1) {
        if (tid < s) sh[tid] += sh[tid + s];
        __syncthreads();
    }
    double r = sh[0];
    __syncthreads();
    return r;
}

// ---------------------------------------------------------------------------
// per-edge losses + per-edge geometry store
// ---------------------------------------------------------------------------
__global__ __launch_bounds__(256) void edge_kernel(
        const float* __restrict__ ep, int E,
        double* __restrict__ normal_part,
        double* __restrict__ norz_part,
        fx4* __restrict__ geom_out,
        int* __restrict__ nh_out) {
    int e = blockIdx.x * blockDim.x + threadIdx.x;
    double t1 = 0.0, t2 = 0.0;
    if (e < E) {
        Geom g = compute_geom(ep, e);
        float pdx = g.p0x - g.p2x, pdy = g.p0y - g.p2y, pdz = g.p0z - g.p2z;
        float pnx = pdy * g.cdz - pdz * g.cdy;
        float pny = pdz * g.cdx - pdx * g.cdz;
        float pnz = pdx * g.cdy - pdy * g.cdx;
        float n = sqrtf(pnx * pnx + pny * pny + pnz * pnz) + 1e-8f;
        pnx /= n; pny /= n; pnz /= n;
        float dotn = g.cnx * pnx + g.cny * pny + g.cnz * pnz;
        t1 = (double)(1.0f - dotn);

        float ox = g.p0y * g.p1z - g.p0z * g.p1y;
        float oy = g.p0z * g.p1x - g.p0x * g.p1z;
        float oz = g.p0x * g.p1y - g.p0y * g.p1x;
        float no = sqrtf(ox * ox + oy * oy + oz * oz) + 1e-8f;
        ox /= no; oy /= no; oz /= no;
        float snp = fminf(fabsf(g.cux * ox + g.cuy * oy + g.cuz * oz), 0.5f);
        t2 = (double)(1.0f - snp / 0.5f);

        fx4 f0 = {g.cdx, g.cdy, g.cdz, g.len};
        fx4 f1 = {g.cux, g.cuy, g.cuz, 1.0f / (float)(g.nh - 1)};
        fx4 f2 = {g.p0x, g.p0y, g.p0z, 0.f};
        geom_out[e * 3 + 0] = f0;
        geom_out[e * 3 + 1] = f1;
        geom_out[e * 3 + 2] = f2;
        nh_out[e] = g.nh;
    }
    double s1 = block_reduce_d(t1);
    double s2 = block_reduce_d(t2);
    if (threadIdx.x == 0) {
        normal_part[blockIdx.x] = s1;
        norz_part[blockIdx.x]   = s2;
    }
}

// ---------------------------------------------------------------------------
// prep: thread-coarsened prefix scan of nh*10 -> cum, plus (thread 0)
// transform = K2h @ E2 @ inv(E1). One launch.
// ---------------------------------------------------------------------------
__global__ __launch_bounds__(256) void prep_kernel(
        const int* __restrict__ nh, int E, unsigned* __restrict__ cum,
        const float* __restrict__ K2, const float* __restrict__ E1,
        const float* __restrict__ E2, float* __restrict__ tf) {
    __shared__ unsigned ssum[256];
    int tid = threadIdx.x;
    int K = (E + 255) / 256;
    int base = tid * K;

    unsigned s = 0;
    for (int k = 0; k < K; ++k) {
        int idx = base + k;
        if (idx < E) s += (unsigned)(nh[idx] * NVS);
    }
    ssum[tid] = s;
    __syncthreads();
    for (int off = 1; off < 256; off <<= 1) {
        unsigned add = (tid >= off) ? ssum[tid - off] : 0u;
        __syncthreads();
        ssum[tid] += add;
        __syncthreads();
    }
    unsigned run = ssum[tid] - s;
    for (int k = 0; k < K; ++k) {
        int idx = base + k;
        if (idx < E) {
            run += (unsigned)(nh[idx] * NVS);
            cum[idx + 1] = run;
        }
    }
    if (tid == 0) {
        cum[0] = 0;

        double a[4][8];
        for (int r = 0; r < 4; ++r)
            for (int c = 0; c < 4; ++c) {
                a[r][c] = (double)E1[r * 4 + c];
                a[r][4 + c] = (r == c) ? 1.0 : 0.0;
            }
        for (int col = 0; col < 4; ++col) {
            int piv = col; double best = fabs(a[col][col]);
            for (int r = col + 1; r < 4; ++r) {
                double t = fabs(a[r][col]);
                if (t > best) { best = t; piv = r; }
            }
            if (piv != col)
                for (int c = 0; c < 8; ++c) { double t = a[col][c]; a[col][c] = a[piv][c]; a[piv][c] = t; }
            double d = a[col][col];
            for (int c = 0; c < 8; ++c) a[col][c] /= d;
            for (int r = 0; r < 4; ++r) {
                if (r == col) continue;
                double f = a[r][col];
                for (int c = 0; c < 8; ++c) a[r][c] -= f * a[col][c];
            }
        }
        double inv1[4][4];
        for (int r = 0; r < 4; ++r)
            for (int c = 0; c < 4; ++c) inv1[r][c] = a[r][4 + c];

        double k2h[4][4];
        for (int r = 0; r < 4; ++r)
            for (int c = 0; c < 4; ++c) k2h[r][c] = (r == c) ? 1.0 : 0.0;
        for (int r = 0; r < 3; ++r)
            for (int c = 0; c < 3; ++c) k2h[r][c] = (double)K2[r * 3 + c];

        double m1[4][4];
        for (int r = 0; r < 4; ++r)
            for (int c = 0; c < 4; ++c) {
                double sm = 0.0;
                for (int k = 0; k < 4; ++k) sm += (double)E2[r * 4 + k] * inv1[k][c];
                m1[r][c] = sm;
            }
        for (int r = 0; r < 4; ++r)
            for (int c = 0; c < 4; ++c) {
                double sm = 0.0;
                for (int k = 0; k < 4; ++k) sm += k2h[r][k] * m1[k][c];
                tf[r * 4 + c] = (float)sm;
            }
    }
}

// ---------------------------------------------------------------------------
// pack helpers: RGB565 dual-pixel. word = p565(x) | p565(x+1)<<16
// ---------------------------------------------------------------------------
__device__ __forceinline__ unsigned p565(float r, float g, float b) {
    unsigned ri = (unsigned)__float2int_rn(r * 31.0f) & 31u;
    unsigned gi = (unsigned)__float2int_rn(g * 63.0f) & 63u;
    unsigned bi = (unsigned)__float2int_rn(b * 31.0f) & 31u;
    return ri | (gi << 5) | (bi << 11);
}

// Neighbor pixel for the (q*4+3, q*4+4) pair comes from lane+1's h0 via
// __shfl_down (waves are uniformly active: 2*nq is a multiple of 64).
__global__ __launch_bounds__(256) void repack_kernel(
        const float* __restrict__ img1, const float* __restrict__ img2,
        unsigned* __restrict__ o1, unsigned* __restrict__ o2) {
    const int nq = NPIX / 4;
    int idx = blockIdx.x * blockDim.x + threadIdx.x;
    bool act = idx < 2 * nq;

    const float* img = img1;
    unsigned* out = o1;
    int q = 0;
    unsigned h0 = 0, h1 = 0, h2 = 0, h3 = 0;
    fx4 r{}, g{}, b{};

    if (act) {
        if (idx < nq) { img = img1; out = o1; q = idx; }
        else          { img = img2; out = o2; q = idx - nq; }
        r = __builtin_nontemporal_load(reinterpret_cast<const fx4*>(img) + q);
        g = __builtin_nontemporal_load(reinterpret_cast<const fx4*>(img + NPIX) + q);
        b = __builtin_nontemporal_load(reinterpret_cast<const fx4*>(img + 2 * (size_t)NPIX) + q);
        h0 = p565(r.x, g.x, b.x);
        h1 = p565(r.y, g.y, b.y);
        h2 = p565(r.z, g.z, b.z);
        h3 = p565(r.w, g.w, b.w);
    }

    unsigned h4s = __shfl_down(h0, 1, 64);   // lane+1's first pixel

    if (act) {
        int qrow = q % QROW;
        unsigned h4;
        if (qrow == QROW - 1) {
            h4 = h3;                          // clamp: last col pairs with itself
        } else if ((threadIdx.x & 63) == 63) {
            int nx = q * 4 + 4;               // rare fallback: wave boundary
            h4 = p565(img[nx], img[NPIX + nx], img[2 * (size_t)NPIX + nx]);
        } else {
            h4 = h4s;
        }
        ux4 o;
        o.x = h0 | (h1 << 16);
        o.y = h1 | (h2 << 16);
        o.z = h2 | (h3 << 16);
        o.w = h3 | (h4 << 16);
        reinterpret_cast<ux4*>(out)[q] = o;
    }
}

// ---------------------------------------------------------------------------
// bilinear sample of dual-565 texture: 2x 4B gathers (rows y0, y1).
// Returns channels in [0,31]/[0,63]/[0,31] scale.
// ---------------------------------------------------------------------------
__device__ __forceinline__ void sample565(const unsigned* __restrict__ img,
                                          float u, float v,
                                          float& r, float& g, float& b) {
    float x = u * (float)IMG_W - 0.5f;
    float y = v * (float)IMG_H - 0.5f;
    float x0 = floorf(x), y0 = floorf(y);
    float wx = x - x0, wy = y - y0;
    int x0i = (int)x0; x0i = x0i < 0 ? 0 : (x0i > IMG_W - 1 ? IMG_W - 1 : x0i);
    int y0i = (int)y0; y0i = y0i < 0 ? 0 : (y0i > IMG_H - 1 ? IMG_H - 1 : y0i);
    int y1i = y0i + 1; y1i = y1i > IMG_H - 1 ? IMG_H - 1 : y1i;

    unsigned t0 = img[(size_t)y0i * IMG_W + x0i];   // (x0, x1) row y0
    unsigned t1 = img[(size_t)y1i * IMG_W + x0i];   // (x0, x1) row y1

    float w00 = (1.f - wx) * (1.f - wy);
    float w10 = wx * (1.f - wy);
    float w01 = (1.f - wx) * wy;
    float w11 = wx * wy;

    r = w00 * (float)(t0 & 31u)         + w10 * (float)((t0 >> 16) & 31u)
      + w01 * (float)(t1 & 31u)         + w11 * (float)((t1 >> 16) & 31u);
    g = w00 * (float)((t0 >> 5) & 63u)  + w10 * (float)((t0 >> 21) & 63u)
      + w01 * (float)((t1 >> 5) & 63u)  + w11 * (float)((t1 >> 21) & 63u);
    b = w00 * (float)((t0 >> 11) & 31u) + w10 * (float)(t0 >> 27)
      + w01 * (float)((t1 >> 11) & 31u) + w11 * (float)(t1 >> 27);
}

// fp32 CHW fallback
__device__ __forceinline__ void bilinear3(const float* __restrict__ img,
                                          float u, float v,
                                          float& r, float& g, float& b) {
    float x = u * (float)IMG_W - 0.5f;
    float y = v * (float)IMG_H - 0.5f;
    float x0 = floorf(x), y0 = floorf(y);
    float wx = x - x0, wy = y - y0;
    int x0i = (int)x0; x0i = x0i < 0 ? 0 : (x0i > IMG_W - 1 ? IMG_W - 1 : x0i);
    int x1i = x0i + 1; x1i = x1i > IMG_W - 1 ? IMG_W - 1 : x1i;
    int y0i = (int)y0; y0i = y0i < 0 ? 0 : (y0i > IMG_H - 1 ? IMG_H - 1 : y0i);
    int y1i = y0i + 1; y1i = y1i > IMG_H - 1 ? IMG_H - 1 : y1i;
    float w00 = (1.f - wx) * (1.f - wy);
    float w10 = wx * (1.f - wy);
    float w01 = (1.f - wx) * wy;
    float w11 = wx * wy;
    float out[3];
#pragma unroll
    for (int c = 0; c < 3; ++c) {
        const float* p = img + (size_t)c * NPIX;
        float v00 = p[(size_t)y0i * IMG_W + x0i];
        float v10 = p[(size_t)y0i * IMG_W + x1i];
        float v01 = p[(size_t)y1i * IMG_W + x0i];
        float v11 = p[(size_t)y1i * IMG_W + x1i];
        out[c] = v00 * w00 + v10 * w10 + v01 * w01 + v11 * w11;
    }
    r = out[0]; g = out[1]; b = out[2];
}

__device__ __forceinline__ int find_edge(const unsigned* __restrict__ cum,
                                         int E, unsigned s) {
    int lo = 0, hi = E - 1;
    while (lo < hi) {
        int mid = (lo + hi + 1) >> 1;
        if (cum[mid] <= s) lo = mid; else hi = mid - 1;
    }
    return lo;
}

// ---------------------------------------------------------------------------
// flattened sampling (R9 structure): grid-stride over 512-sample chunks,
// 2 samples/thread, register accumulation, ONE block reduce at the end.
// ---------------------------------------------------------------------------
template <bool PACKED>
__global__ __launch_bounds__(256) void sample_kernel_t(
        const fx4* __restrict__ geom,
        const unsigned* __restrict__ cum, int E,
        const void* __restrict__ vimg1,
        const void* __restrict__ vimg2,
        const float* __restrict__ K1,
        const float* __restrict__ tf,
        double* __restrict__ sim_part) {
    __shared__ int sh_ea[2], sh_eb[2];
    int tid = threadIdx.x;

    unsigned NS = cum[E];
    unsigned nch = (NS + CHUNK - 1u) / CHUNK;

    float k00 = K1[0], k01 = K1[1], k02 = K1[2];
    float k10 = K1[3], k11 = K1[4], k12 = K1[5];
    float k20 = K1[6], k21 = K1[7], k22 = K1[8];
    float t00 = tf[0],  t01 = tf[1],  t02 = tf[2],  t03 = tf[3];
    float t10 = tf[4],  t11 = tf[5],  t12 = tf[6],  t13 = tf[7];
    float t20 = tf[8],  t21 = tf[9],  t22 = tf[10], t23 = tf[11];

    const unsigned* img1 = (const unsigned*)vimg1;
    const unsigned* img2 = (const unsigned*)vimg2;
    const float* fimg1 = (const float*)vimg1;
    const float* fimg2 = (const float*)vimg2;

    const float INV31 = 1.0f / 31.0f;
    const float INV63 = 1.0f / 63.0f;

    double lsum = 0.0;
    int it = 0;

    auto sample_one = [&](unsigned s, int e) {
        while (e + 1 < E && cum[e + 1] <= s) ++e;
        unsigned q = s - cum[e];
        int i = (int)(q / (unsigned)NVS);
        int j = (int)(q - (unsigned)(i * NVS));

        fx4 f0 = geom[e * 3 + 0];
        fx4 f1 = geom[e * 3 + 1];
        fx4 f2 = geom[e * 3 + 2];

        float dxv = ((float)i * f1.w) * f0.w;
        float dyv = ((float)j / 9.0f) * 0.5f;

        float px = f0.x * dxv + f1.x * dyv + f2.x;
        float py = f0.y * dxv + f1.y * dyv + f2.y;
        float pz = f0.z * dxv + f1.z * dyv + f2.z;

        float w1 = k20 * px + k21 * py + k22 * pz;
        float u1 = (k00 * px + k01 * py + k02 * pz) / w1;
        float v1 = (k10 * px + k11 * py + k12 * pz) / w1;
        u1 = fminf(fmaxf(u1, 0.f), 0.999999f);
        v1 = fminf(fmaxf(v1, 0.f), 0.999999f);

        float w2 = t20 * px + t21 * py + t22 * pz + t23;
        float u2 = (t00 * px + t01 * py + t02 * pz + t03) / w2;
        float v2 = (t10 * px + t11 * py + t12 * pz + t13) / w2;
        u2 = fminf(fmaxf(u2, 0.f), 0.999999f);
        v2 = fminf(fmaxf(v2, 0.f), 0.999999f);

        if constexpr (PACKED) {
            float ar, ag, ab, br, bg, bb;
            sample565(img1, u1, v1, ar, ag, ab);
            sample565(img2, u2, v2, br, bg, bb);
            float dr = (ar - br) * INV31;
            float dg = (ag - bg) * INV63;
            float db = (ab - bb) * INV31;
            lsum += (double)(dr * dr) + (double)(dg * dg) + (double)(db * db);
        } else {
            float ar, ag, ab, br, bg, bb;
            bilinear3(fimg1, u1, v1, ar, ag, ab);
            bilinear3(fimg2, u2, v2, br, bg, bb);
            float dr = ar - br, dg = ag - bg, db = ab - bb;
            lsum += (double)(dr * dr) + (double)(dg * dg) + (double)(db * db);
        }
    };

    for (unsigned chunk = blockIdx.x; chunk < nch; chunk += gridDim.x, ++it) {
        unsigned sbase = chunk * CHUNK;
        int par = it & 1;
        if (tid == 0) {
            sh_ea[par] = find_edge(cum, E, sbase);
            unsigned smid = sbase + 256u;
            sh_eb[par] = find_edge(cum, E, smid < NS ? smid : NS - 1u);
        }
        __syncthreads();
        int ea = sh_ea[par];
        int eb = sh_eb[par];

        unsigned sA = sbase + (unsigned)tid;
        unsigned sB = sA + 256u;
        if (sA < NS) sample_one(sA, ea);
        if (sB < NS) sample_one(sB, eb);
    }

    double tot = block_reduce_d(lsum);
    if (tid == 0) sim_part[blockIdx.x] = tot;
}

// ---------------------------------------------------------------------------
// finalize
// ---------------------------------------------------------------------------
__global__ __launch_bounds__(256) void finalize_kernel(
        const double* __restrict__ sim_part, int n_sim,
        const unsigned* __restrict__ cum, int E,
        const double* __restrict__ normal_part,
        const double* __restrict__ norz_part, int n_a,
        float* __restrict__ out) {
    int tid = threadIdx.x;
    unsigned NS = cum[E];

    double s = 0.0;
    for (int i = tid; i < n_sim; i += 256) s += sim_part[i];
    double sim = block_reduce_d(s);

    s = 0.0;
    for (int i = tid; i < n_a; i += 256) s += normal_part[i];
    double nrm = block_reduce_d(s);

    s = 0.0;
    for (int i = tid; i < n_a; i += 256) s += norz_part[i];
    double nz = block_reduce_d(s);

    if (tid == 0) {
        double total = (double)NS * 3.0;
        out[0] = (float)(sim / total);
        out[1] = (float)((nrm / (double)E) * 0.5);
        out[2] = (float)(nz / (double)E);
    }
}

// ---------------------------------------------------------------------------
extern "C" void kernel_launch(void* const* d_in, const int* in_sizes, int n_in,
                              void* d_out, int out_size, void* d_ws, size_t ws_size,
                              hipStream_t stream) {
    const float* ep  = (const float*)d_in[0];
    const float* im1 = (const float*)d_in[1];
    const float* im2 = (const float*)d_in[2];
    const float* K1  = (const float*)d_in[3];
    const float* K2  = (const float*)d_in[4];
    const float* E1  = (const float*)d_in[5];
    const float* E2  = (const float*)d_in[6];
    float* out = (float*)d_out;

    int E  = in_sizes[0] / 12;
    int nA = (E + 255) / 256;

    size_t img_bytes = (size_t)NPIX * 4;   // dual-565, 4B/pixel

    char* ws = (char*)d_ws;
    size_t off = 0;
    auto alloc = [&](size_t bytes) {
        size_t o = off;
        off = (off + bytes + 255) & ~(size_t)255;
        return (void*)(ws + o);
    };

    fx4*      geom        = (fx4*)alloc((size_t)E * 48);
    int*      nh_arr      = (int*)alloc((size_t)E * 4);
    unsigned* cum         = (unsigned*)alloc((size_t)(E + 1) * 4);
    float*    tf          = (float*)alloc(64);
    double*   sim_part    = (double*)alloc((size_t)SAMPLE_BLOCKS * 8);
    double*   normal_part = (double*)alloc((size_t)nA * 8);
    double*   norz_part   = (double*)alloc((size_t)nA * 8);
    size_t tail_bytes = off;

    bool packed = ws_size >= tail_bytes + 2 * img_bytes + 512;
    unsigned* p1 = nullptr;
    unsigned* p2 = nullptr;
    if (packed) {
        p1 = (unsigned*)alloc(img_bytes);
        p2 = (unsigned*)alloc(img_bytes);
    }

    edge_kernel<<<nA, 256, 0, stream>>>(ep, E, normal_part, norz_part, geom, nh_arr);
    prep_kernel<<<1, 256, 0, stream>>>(nh_arr, E, cum, K2, E1, E2, tf);
    if (packed) {
        const int nq2 = 2 * (NPIX / 4);
        repack_kernel<<<(nq2 + 255) / 256, 256, 0, stream>>>(im1, im2, p1, p2);
        sample_kernel_t<true><<<SAMPLE_BLOCKS, 256, 0, stream>>>(
            geom, cum, E, (const void*)p1, (const void*)p2, K1, tf, sim_part);
    } else {
        sample_kernel_t<false><<<SAMPLE_BLOCKS, 256, 0, stream>>>(
            geom, cum, E, (const void*)im1, (const void*)im2, K1, tf, sim_part);
    }
    finalize_kernel<<<1, 256, 0, stream>>>(sim_part, SAMPLE_BLOCKS, cum, E,
                                           normal_part, norz_part, nA, out);
}